// Round 2
// baseline (1503.952 us; speedup 1.0000x reference)
//
#include <hip/hip_runtime.h>

#define NODES 100000
#define EDGES 1600000
#define IN_DIM 128
#define HID_DIM 128
#define OUT_DIM 64

__global__ void k_init_deg(float* __restrict__ deg) {
    int i = blockIdx.x * 256 + threadIdx.x;
    if (i < NODES) deg[i] = 1.0f;  // self-loop contribution
}

__global__ void k_count_deg(const int* __restrict__ dst, float* __restrict__ deg) {
    int e = blockIdx.x * 256 + threadIdx.x;
    if (e < EDGES) atomicAdd(&deg[dst[e]], 1.0f);
}

__global__ void k_dis(float* __restrict__ deg) {
    int i = blockIdx.x * 256 + threadIdx.x;
    if (i < NODES) deg[i] = rsqrtf(deg[i]);  // deg>=1 always (self-loop)
}

__global__ void k_norm(const int* __restrict__ src, const int* __restrict__ dst,
                       const float* __restrict__ dis, float* __restrict__ norm) {
    int e = blockIdx.x * 256 + threadIdx.x;
    if (e < EDGES) norm[e] = dis[src[e]] * dis[dst[e]];
}

// h = x @ W1 ; agg = b1 + h * dis^2 (self-loop init of aggregation buffer)
// block = 256 threads = 2 rows x 128 cols
__global__ void k_gemm1(const float* __restrict__ x, const float* __restrict__ W1,
                        const float* __restrict__ b1, const float* __restrict__ dis,
                        float* __restrict__ h, float* __restrict__ agg) {
    __shared__ float xs[2][IN_DIM];
    const int r = threadIdx.x >> 7;        // 0..1
    const int j = threadIdx.x & 127;       // 0..127
    const int row = blockIdx.x * 2 + r;
    xs[r][j] = x[(size_t)row * IN_DIM + j];
    __syncthreads();
    float acc = 0.0f;
    const float* xr = xs[r];
#pragma unroll
    for (int k = 0; k < IN_DIM; ++k)
        acc = fmaf(xr[k], W1[k * HID_DIM + j], acc);
    h[(size_t)row * HID_DIM + j] = acc;
    const float d = dis[row];
    agg[(size_t)row * HID_DIM + j] = b1[j] + acc * d * d;
}

// agg[dst] += norm[e] * h[src] ; one thread per (edge, dim)
__global__ void k_agg1(const int* __restrict__ src, const int* __restrict__ dst,
                       const float* __restrict__ norm, const float* __restrict__ h,
                       float* __restrict__ agg) {
    int idx = blockIdx.x * 256 + threadIdx.x;   // < EDGES*128 = 204.8M, fits int
    int e = idx >> 7;
    int j = idx & 127;
    int s = src[e], d = dst[e];
    atomicAdd(&agg[(size_t)d * HID_DIM + j], norm[e] * h[(size_t)s * HID_DIM + j]);
}

// g = relu(agg1) @ W2 ; out = b2 + g * dis^2
// block = 256 threads = 4 rows x 64 cols
__global__ void k_gemm2(const float* __restrict__ agg1, const float* __restrict__ W2,
                        const float* __restrict__ b2, const float* __restrict__ dis,
                        float* __restrict__ g, float* __restrict__ out) {
    __shared__ float hs[4][HID_DIM];
    const int r = threadIdx.x >> 6;        // 0..3
    const int j = threadIdx.x & 63;        // 0..63
    const int row = blockIdx.x * 4 + r;
    hs[r][j]      = fmaxf(agg1[(size_t)row * HID_DIM + j], 0.0f);
    hs[r][j + 64] = fmaxf(agg1[(size_t)row * HID_DIM + j + 64], 0.0f);
    __syncthreads();
    float acc = 0.0f;
#pragma unroll
    for (int k = 0; k < HID_DIM; ++k)
        acc = fmaf(hs[r][k], W2[k * OUT_DIM + j], acc);
    g[(size_t)row * OUT_DIM + j] = acc;
    const float d = dis[row];
    out[(size_t)row * OUT_DIM + j] = b2[j] + acc * d * d;
}

// out[dst] += norm[e] * g[src] ; one thread per (edge, dim)
__global__ void k_agg2(const int* __restrict__ src, const int* __restrict__ dst,
                       const float* __restrict__ norm, const float* __restrict__ g,
                       float* __restrict__ out) {
    int idx = blockIdx.x * 256 + threadIdx.x;   // < EDGES*64 = 102.4M, fits int
    int e = idx >> 6;
    int j = idx & 63;
    int s = src[e], d = dst[e];
    atomicAdd(&out[(size_t)d * OUT_DIM + j], norm[e] * g[(size_t)s * OUT_DIM + j]);
}

extern "C" void kernel_launch(void* const* d_in, const int* in_sizes, int n_in,
                              void* d_out, int out_size, void* d_ws, size_t ws_size,
                              hipStream_t stream) {
    const float* x  = (const float*)d_in[0];
    const float* W1 = (const float*)d_in[1];
    const float* b1 = (const float*)d_in[2];
    const float* W2 = (const float*)d_in[3];
    const float* b2 = (const float*)d_in[4];
    const int*   ei = (const int*)d_in[5];   // int32 (JAX default: x64 disabled)
    const int* src = ei;
    const int* dst = ei + EDGES;

    float* out = (float*)d_out;
    float* ws  = (float*)d_ws;

    float* deg  = ws;                                 // N floats (becomes dis)
    float* norm = deg + NODES;                        // E floats
    float* buf1 = norm + EDGES;                       // N*128 (h, later g)
    float* buf2 = buf1 + (size_t)NODES * HID_DIM;     // N*128 (agg1 result)

    k_init_deg<<<(NODES + 255) / 256, 256, 0, stream>>>(deg);
    k_count_deg<<<(EDGES + 255) / 256, 256, 0, stream>>>(dst, deg);
    k_dis<<<(NODES + 255) / 256, 256, 0, stream>>>(deg);
    k_norm<<<(EDGES + 255) / 256, 256, 0, stream>>>(src, dst, deg, norm);

    k_gemm1<<<NODES / 2, 256, 0, stream>>>(x, W1, b1, deg, buf1, buf2);
    k_agg1<<<(EDGES * 128) / 256, 256, 0, stream>>>(src, dst, norm, buf1, buf2);
    k_gemm2<<<NODES / 4, 256, 0, stream>>>(buf2, W2, b2, deg, buf1, out);
    k_agg2<<<(EDGES * 64) / 256, 256, 0, stream>>>(src, dst, norm, buf1, out);
}

// Round 4
// 820.357 us; speedup vs baseline: 1.8333x; 1.8333x over previous
//
#include <hip/hip_runtime.h>

#define NODES 100000
#define EDGES 1600000
#define IN_DIM 128
#define HID_DIM 128
#define OUT_DIM 64
#define NBLK 98          // ceil(100000 / 1024) scan blocks

// ---------------- preprocessing: CSR by dst ----------------

__global__ void k_zero(int* __restrict__ cnt) {
    int i = blockIdx.x * 256 + threadIdx.x;
    if (i < NODES) cnt[i] = 0;
}

__global__ void k_count(const int* __restrict__ dst, int* __restrict__ cnt) {
    int e = blockIdx.x * 256 + threadIdx.x;
    if (e < EDGES) atomicAdd(&cnt[dst[e]], 1);
}

// per-block sums of 1024 counts
__global__ void k_scanA(const int* __restrict__ cnt, int* __restrict__ bsums) {
    __shared__ int sh[256];
    int t = threadIdx.x;
    int base = blockIdx.x * 1024 + t * 4;
    int sum = 0;
    for (int u = 0; u < 4; ++u) {
        int i = base + u;
        if (i < NODES) sum += cnt[i];
    }
    sh[t] = sum; __syncthreads();
    for (int off = 128; off > 0; off >>= 1) {
        if (t < off) sh[t] += sh[t + off];
        __syncthreads();
    }
    if (t == 0) bsums[blockIdx.x] = sh[0];
}

// exclusive scan of the 98 block sums (single block, 128 threads)
__global__ void k_scanB(int* __restrict__ bsums) {
    __shared__ int sh[128];
    int t = threadIdx.x;
    int v = (t < NBLK) ? bsums[t] : 0;
    sh[t] = v; __syncthreads();
    for (int off = 1; off < 128; off <<= 1) {
        int add = (t >= off) ? sh[t - off] : 0;
        __syncthreads();
        sh[t] += add;
        __syncthreads();
    }
    if (t < NBLK) bsums[t] = sh[t] - v;   // exclusive
}

// block-local exclusive scan + global offset -> rowptr, cursor, dis
__global__ void k_scanC(const int* __restrict__ cnt, const int* __restrict__ bsums,
                        int* __restrict__ rowptr, int* __restrict__ cursor,
                        float* __restrict__ dis) {
    __shared__ int sh[256];
    int t = threadIdx.x;
    int base = blockIdx.x * 1024 + t * 4;
    int c[4]; int sum = 0;
    for (int u = 0; u < 4; ++u) {
        int i = base + u;
        c[u] = (i < NODES) ? cnt[i] : 0;
        sum += c[u];
    }
    sh[t] = sum; __syncthreads();
    for (int off = 1; off < 256; off <<= 1) {
        int add = (t >= off) ? sh[t - off] : 0;
        __syncthreads();
        sh[t] += add;
        __syncthreads();
    }
    int excl = sh[t] - sum + bsums[blockIdx.x];
    for (int u = 0; u < 4; ++u) {
        int i = base + u;
        if (i < NODES) {
            rowptr[i] = excl;
            cursor[i] = excl;
            dis[i] = rsqrtf((float)(1 + c[u]));   // deg = in-degree + self-loop
            excl += c[u];
            if (i == NODES - 1) rowptr[NODES] = excl;
        }
    }
}

__global__ void k_scatter(const int* __restrict__ src, const int* __restrict__ dst,
                          int* __restrict__ cursor, int* __restrict__ ssrc) {
    int e = blockIdx.x * 256 + threadIdx.x;
    if (e < EDGES) {
        int d = dst[e];
        int pos = atomicAdd(&cursor[d], 1);
        ssrc[pos] = src[e];
    }
}

// ---------------- GEMMs (register-tiled) ----------------

// h = x @ W1 ; 16 rows/block, thread = 2 rows x 4 cols
__global__ __launch_bounds__(256) void k_gemm1(const float* __restrict__ x,
                                               const float* __restrict__ W1,
                                               float* __restrict__ h) {
    __shared__ float xs[16][130];
    const int t = threadIdx.x;
    const int row0 = blockIdx.x * 16;
    {
        int r = t >> 4, c = (t & 15) * 8;
        const float4* sp = (const float4*)&x[(size_t)(row0 + r) * 128 + c];
        float4 a = sp[0], b = sp[1];
        xs[r][c + 0] = a.x; xs[r][c + 1] = a.y; xs[r][c + 2] = a.z; xs[r][c + 3] = a.w;
        xs[r][c + 4] = b.x; xs[r][c + 5] = b.y; xs[r][c + 6] = b.z; xs[r][c + 7] = b.w;
    }
    __syncthreads();
    const int c4 = (t & 31) * 4;
    const int r2 = (t >> 5) * 2;
    float4 acc0 = {0, 0, 0, 0}, acc1 = {0, 0, 0, 0};
#pragma unroll 4
    for (int k = 0; k < 128; ++k) {
        float4 w = *(const float4*)&W1[k * HID_DIM + c4];
        float a0 = xs[r2][k], a1 = xs[r2 + 1][k];
        acc0.x = fmaf(a0, w.x, acc0.x); acc0.y = fmaf(a0, w.y, acc0.y);
        acc0.z = fmaf(a0, w.z, acc0.z); acc0.w = fmaf(a0, w.w, acc0.w);
        acc1.x = fmaf(a1, w.x, acc1.x); acc1.y = fmaf(a1, w.y, acc1.y);
        acc1.z = fmaf(a1, w.z, acc1.z); acc1.w = fmaf(a1, w.w, acc1.w);
    }
    *(float4*)&h[(size_t)(row0 + r2) * 128 + c4] = acc0;
    *(float4*)&h[(size_t)(row0 + r2 + 1) * 128 + c4] = acc1;
}

// g = relu(agg) @ W2 ; 16 rows/block, thread = 1 row x 4 cols
__global__ __launch_bounds__(256) void k_gemm2(const float* __restrict__ agg,
                                               const float* __restrict__ W2,
                                               float* __restrict__ g) {
    __shared__ float hs[16][130];
    const int t = threadIdx.x;
    const int row0 = blockIdx.x * 16;
    {
        int r = t >> 4, c = (t & 15) * 8;
        const float4* sp = (const float4*)&agg[(size_t)(row0 + r) * 128 + c];
        float4 a = sp[0], b = sp[1];
        hs[r][c + 0] = fmaxf(a.x, 0.f); hs[r][c + 1] = fmaxf(a.y, 0.f);
        hs[r][c + 2] = fmaxf(a.z, 0.f); hs[r][c + 3] = fmaxf(a.w, 0.f);
        hs[r][c + 4] = fmaxf(b.x, 0.f); hs[r][c + 5] = fmaxf(b.y, 0.f);
        hs[r][c + 6] = fmaxf(b.z, 0.f); hs[r][c + 7] = fmaxf(b.w, 0.f);
    }
    __syncthreads();
    const int c4 = (t & 15) * 4;
    const int r = t >> 4;
    float4 acc = {0, 0, 0, 0};
#pragma unroll 4
    for (int k = 0; k < 128; ++k) {
        float4 w = *(const float4*)&W2[k * OUT_DIM + c4];
        float a = hs[r][k];
        acc.x = fmaf(a, w.x, acc.x); acc.y = fmaf(a, w.y, acc.y);
        acc.z = fmaf(a, w.z, acc.z); acc.w = fmaf(a, w.w, acc.w);
    }
    *(float4*)&g[(size_t)(row0 + r) * 64 + c4] = acc;
}

// ---------------- CSR aggregation (atomic-free) ----------------

// agg[v] = b1 + dis[v]*( dis[v]*h[v] + sum_{s in N(v)} dis[s]*h[s] )
// 4 nodes/block, 1 wave per node, thread = 2 dims (float2)
__global__ void k_agg1(const int* __restrict__ rowptr, const int* __restrict__ ssrc,
                       const float* __restrict__ dis, const float* __restrict__ h,
                       const float* __restrict__ b1, float* __restrict__ agg) {
    const int t = threadIdx.x;
    const int v = blockIdx.x * 4 + (t >> 6);
    const int j = t & 63;                       // dim pair
    const float2* h2 = (const float2*)h;
    const float dv = dis[v];
    float2 hv = h2[(size_t)v * 64 + j];
    float ax = dv * hv.x, ay = dv * hv.y;
    int e = rowptr[v];
    const int end = rowptr[v + 1];
    for (; e < end; ++e) {
        int s = ssrc[e];
        float dsv = dis[s];
        float2 hsv = h2[(size_t)s * 64 + j];
        ax = fmaf(dsv, hsv.x, ax);
        ay = fmaf(dsv, hsv.y, ay);
    }
    float2 bb = ((const float2*)b1)[j];
    float2 o;
    o.x = fmaf(dv, ax, bb.x);
    o.y = fmaf(dv, ay, bb.y);
    ((float2*)agg)[(size_t)v * 64 + j] = o;
}

// out[v] = b2 + dis[v]*( dis[v]*g[v] + sum dis[s]*g[s] )
// 4 nodes/block, 1 wave per node, thread = 1 dim
__global__ void k_agg2(const int* __restrict__ rowptr, const int* __restrict__ ssrc,
                       const float* __restrict__ dis, const float* __restrict__ g,
                       const float* __restrict__ b2, float* __restrict__ out) {
    const int t = threadIdx.x;
    const int v = blockIdx.x * 4 + (t >> 6);
    const int j = t & 63;
    const float dv = dis[v];
    float acc = dv * g[(size_t)v * 64 + j];
    int e = rowptr[v];
    const int end = rowptr[v + 1];
    for (; e < end; ++e) {
        int s = ssrc[e];
        acc = fmaf(dis[s], g[(size_t)s * 64 + j], acc);
    }
    out[(size_t)v * 64 + j] = fmaf(dv, acc, b2[j]);
}

// ---------------- launch ----------------

extern "C" void kernel_launch(void* const* d_in, const int* in_sizes, int n_in,
                              void* d_out, int out_size, void* d_ws, size_t ws_size,
                              hipStream_t stream) {
    const float* x  = (const float*)d_in[0];
    const float* W1 = (const float*)d_in[1];
    const float* b1 = (const float*)d_in[2];
    const float* W2 = (const float*)d_in[3];
    const float* b2 = (const float*)d_in[4];
    const int*   ei = (const int*)d_in[5];   // int32 (verified round 2: passed)
    const int* src = ei;
    const int* dst = ei + EDGES;
    float* out = (float*)d_out;

    // workspace layout (element offsets, all 16B-aligned)
    int*   cnt    = (int*)d_ws;                          // N
    int*   rowptr = cnt + 100000;                        // N+1 (reserve 100004)
    int*   cursor = rowptr + 100004;                     // N
    float* dis    = (float*)(cursor + 100000);           // N
    int*   bsums  = (int*)(dis + 100000);                // 128
    int*   ssrc   = bsums + 128;                         // E
    float* buf1   = (float*)(ssrc + EDGES);              // N*128 (h, then g)
    float* buf2   = buf1 + (size_t)NODES * 128;          // N*128 (agg1)

    k_zero   <<<(NODES + 255) / 256, 256, 0, stream>>>(cnt);
    k_count  <<<EDGES / 256, 256, 0, stream>>>(dst, cnt);
    k_scanA  <<<NBLK, 256, 0, stream>>>(cnt, bsums);
    k_scanB  <<<1, 128, 0, stream>>>(bsums);
    k_scanC  <<<NBLK, 256, 0, stream>>>(cnt, bsums, rowptr, cursor, dis);
    k_scatter<<<EDGES / 256, 256, 0, stream>>>(src, dst, cursor, ssrc);

    k_gemm1  <<<NODES / 16, 256, 0, stream>>>(x, W1, buf1);
    k_agg1   <<<NODES / 4, 256, 0, stream>>>(rowptr, ssrc, dis, buf1, b1, buf2);
    k_gemm2  <<<NODES / 16, 256, 0, stream>>>(buf2, W2, buf1);
    k_agg2   <<<NODES / 4, 256, 0, stream>>>(rowptr, ssrc, dis, buf1, b2, out);
}

// Round 5
// 573.860 us; speedup vs baseline: 2.6208x; 1.4295x over previous
//
#include <hip/hip_runtime.h>

#define NODES 100000
#define EDGES 1600000
#define NBLK 98          // ceil(100000 / 1024) scan blocks

typedef unsigned int uint;
typedef unsigned short ushort;

__device__ __forceinline__ float bf2f(uint u) {
    union { uint i; float f; } c; c.i = u << 16; return c.f;
}
__device__ __forceinline__ ushort f2bf(float f) {
    union { float f; uint i; } c; c.f = f;
    uint r = c.i + 0x7fff + ((c.i >> 16) & 1);   // round-to-nearest-even
    return (ushort)(r >> 16);
}

// ---------------- preprocessing: CSR by dst ----------------

__global__ void k_zero(int* __restrict__ cnt) {
    int i = blockIdx.x * 256 + threadIdx.x;
    if (i < NODES) cnt[i] = 0;
}

__global__ void k_count(const int* __restrict__ dst, int* __restrict__ cnt) {
    int i = blockIdx.x * 256 + threadIdx.x;
    if (i < EDGES / 4) {
        int4 d = ((const int4*)dst)[i];
        atomicAdd(&cnt[d.x], 1); atomicAdd(&cnt[d.y], 1);
        atomicAdd(&cnt[d.z], 1); atomicAdd(&cnt[d.w], 1);
    }
}

__global__ void k_scanA(const int* __restrict__ cnt, int* __restrict__ bsums) {
    __shared__ int sh[256];
    int t = threadIdx.x;
    int base = blockIdx.x * 1024 + t * 4;
    int sum = 0;
    for (int u = 0; u < 4; ++u) {
        int i = base + u;
        if (i < NODES) sum += cnt[i];
    }
    sh[t] = sum; __syncthreads();
    for (int off = 128; off > 0; off >>= 1) {
        if (t < off) sh[t] += sh[t + off];
        __syncthreads();
    }
    if (t == 0) bsums[blockIdx.x] = sh[0];
}

__global__ void k_scanB(int* __restrict__ bsums) {
    __shared__ int sh[128];
    int t = threadIdx.x;
    int v = (t < NBLK) ? bsums[t] : 0;
    sh[t] = v; __syncthreads();
    for (int off = 1; off < 128; off <<= 1) {
        int add = (t >= off) ? sh[t - off] : 0;
        __syncthreads();
        sh[t] += add;
        __syncthreads();
    }
    if (t < NBLK) bsums[t] = sh[t] - v;   // exclusive
}

__global__ void k_scanC(const int* __restrict__ cnt, const int* __restrict__ bsums,
                        int* __restrict__ rowptr, int* __restrict__ cursor,
                        float* __restrict__ dis) {
    __shared__ int sh[256];
    int t = threadIdx.x;
    int base = blockIdx.x * 1024 + t * 4;
    int c[4]; int sum = 0;
    for (int u = 0; u < 4; ++u) {
        int i = base + u;
        c[u] = (i < NODES) ? cnt[i] : 0;
        sum += c[u];
    }
    sh[t] = sum; __syncthreads();
    for (int off = 1; off < 256; off <<= 1) {
        int add = (t >= off) ? sh[t - off] : 0;
        __syncthreads();
        sh[t] += add;
        __syncthreads();
    }
    int excl = sh[t] - sum + bsums[blockIdx.x];
    for (int u = 0; u < 4; ++u) {
        int i = base + u;
        if (i < NODES) {
            rowptr[i] = excl;
            cursor[i] = excl;
            dis[i] = rsqrtf((float)(1 + c[u]));
            excl += c[u];
            if (i == NODES - 1) rowptr[NODES] = excl;
        }
    }
}

__global__ void k_scatter(const int* __restrict__ src, const int* __restrict__ dst,
                          int* __restrict__ cursor, int* __restrict__ ssrc) {
    int i = blockIdx.x * 256 + threadIdx.x;
    if (i < EDGES / 4) {
        int4 s = ((const int4*)src)[i];
        int4 d = ((const int4*)dst)[i];
        ssrc[atomicAdd(&cursor[d.x], 1)] = s.x;
        ssrc[atomicAdd(&cursor[d.y], 1)] = s.y;
        ssrc[atomicAdd(&cursor[d.z], 1)] = s.z;
        ssrc[atomicAdd(&cursor[d.w], 1)] = s.w;
    }
}

// ---------------- GEMMs: W staged in LDS, bf16 outputs ----------------

// h = x @ W1  (32 rows/block, thread = 4 rows x 4 cols), out bf16
__global__ __launch_bounds__(256) void k_gemm1(const float* __restrict__ x,
                                               const float* __restrict__ W1,
                                               ushort* __restrict__ hb) {
    __shared__ float wsh[128 * 128];   // 64 KB
    __shared__ float xs[32 * 128];     // 16 KB
    const int t = threadIdx.x;
    {
        const float4* Wv = (const float4*)W1;
        float4* Sv = (float4*)wsh;
#pragma unroll
        for (int i = 0; i < 16; ++i) Sv[i * 256 + t] = Wv[i * 256 + t];
    }
    const int row0 = blockIdx.x * 32;
    {
        const float4* Xv = (const float4*)(x + (size_t)row0 * 128);
        float4* Sv = (float4*)xs;
#pragma unroll
        for (int i = 0; i < 4; ++i) Sv[i * 256 + t] = Xv[i * 256 + t];
    }
    __syncthreads();
    const int c4 = (t & 31) * 4;
    const int r0 = (t >> 5) * 4;
    float4 a0{0,0,0,0}, a1{0,0,0,0}, a2{0,0,0,0}, a3{0,0,0,0};
#pragma unroll 4
    for (int k = 0; k < 128; ++k) {
        float4 w = *(const float4*)&wsh[k * 128 + c4];
        float x0 = xs[(r0 + 0) * 128 + k];
        float x1 = xs[(r0 + 1) * 128 + k];
        float x2 = xs[(r0 + 2) * 128 + k];
        float x3 = xs[(r0 + 3) * 128 + k];
        a0.x = fmaf(x0, w.x, a0.x); a0.y = fmaf(x0, w.y, a0.y);
        a0.z = fmaf(x0, w.z, a0.z); a0.w = fmaf(x0, w.w, a0.w);
        a1.x = fmaf(x1, w.x, a1.x); a1.y = fmaf(x1, w.y, a1.y);
        a1.z = fmaf(x1, w.z, a1.z); a1.w = fmaf(x1, w.w, a1.w);
        a2.x = fmaf(x2, w.x, a2.x); a2.y = fmaf(x2, w.y, a2.y);
        a2.z = fmaf(x2, w.z, a2.z); a2.w = fmaf(x2, w.w, a2.w);
        a3.x = fmaf(x3, w.x, a3.x); a3.y = fmaf(x3, w.y, a3.y);
        a3.z = fmaf(x3, w.z, a3.z); a3.w = fmaf(x3, w.w, a3.w);
    }
    size_t base = (size_t)(row0 + r0) * 128 + c4;
    ushort4 u;
    u.x = f2bf(a0.x); u.y = f2bf(a0.y); u.z = f2bf(a0.z); u.w = f2bf(a0.w);
    *(ushort4*)&hb[base] = u;
    u.x = f2bf(a1.x); u.y = f2bf(a1.y); u.z = f2bf(a1.z); u.w = f2bf(a1.w);
    *(ushort4*)&hb[base + 128] = u;
    u.x = f2bf(a2.x); u.y = f2bf(a2.y); u.z = f2bf(a2.z); u.w = f2bf(a2.w);
    *(ushort4*)&hb[base + 256] = u;
    u.x = f2bf(a3.x); u.y = f2bf(a3.y); u.z = f2bf(a3.z); u.w = f2bf(a3.w);
    *(ushort4*)&hb[base + 384] = u;
}

// g = relu(agg) @ W2  (32 rows/block, thread = 2 rows x 4 cols), out bf16
__global__ __launch_bounds__(256) void k_gemm2(const float* __restrict__ agg,
                                               const float* __restrict__ W2,
                                               ushort* __restrict__ gb) {
    __shared__ float wsh[128 * 64];    // 32 KB
    __shared__ float xs[32 * 132];     // 16.5 KB, padded stride 132
    const int t = threadIdx.x;
    {
        const float4* Wv = (const float4*)W2;
        float4* Sv = (float4*)wsh;
#pragma unroll
        for (int i = 0; i < 8; ++i) Sv[i * 256 + t] = Wv[i * 256 + t];
    }
    const int row0 = blockIdx.x * 32;
    {
        const float4* Xv = (const float4*)(agg + (size_t)row0 * 128);
#pragma unroll
        for (int i = 0; i < 4; ++i) {
            int f = i * 256 + t;
            float4 v = Xv[f];
            int row = f >> 5, cc = (f & 31) * 4;
            float4 rv{fmaxf(v.x, 0.f), fmaxf(v.y, 0.f), fmaxf(v.z, 0.f), fmaxf(v.w, 0.f)};
            *(float4*)&xs[row * 132 + cc] = rv;
        }
    }
    __syncthreads();
    const int c4 = (t & 15) * 4;
    const int r0 = (t >> 4) * 2;
    float4 a0{0,0,0,0}, a1{0,0,0,0};
#pragma unroll 4
    for (int k = 0; k < 128; ++k) {
        float4 w = *(const float4*)&wsh[k * 64 + c4];
        float x0 = xs[(r0 + 0) * 132 + k];
        float x1 = xs[(r0 + 1) * 132 + k];
        a0.x = fmaf(x0, w.x, a0.x); a0.y = fmaf(x0, w.y, a0.y);
        a0.z = fmaf(x0, w.z, a0.z); a0.w = fmaf(x0, w.w, a0.w);
        a1.x = fmaf(x1, w.x, a1.x); a1.y = fmaf(x1, w.y, a1.y);
        a1.z = fmaf(x1, w.z, a1.z); a1.w = fmaf(x1, w.w, a1.w);
    }
    size_t base = (size_t)(row0 + r0) * 64 + c4;
    ushort4 u;
    u.x = f2bf(a0.x); u.y = f2bf(a0.y); u.z = f2bf(a0.z); u.w = f2bf(a0.w);
    *(ushort4*)&gb[base] = u;
    u.x = f2bf(a1.x); u.y = f2bf(a1.y); u.z = f2bf(a1.z); u.w = f2bf(a1.w);
    *(ushort4*)&gb[base + 64] = u;
}

// ---------------- CSR aggregation (bf16 gathers, f32 accumulate) ----------------

// agg[v] = b1 + dis[v]*( dis[v]*h[v] + sum dis[s]*h[s] ) ; wave/node, lane = 2 dims
__global__ void k_agg1(const int* __restrict__ rowptr, const int* __restrict__ ssrc,
                       const float* __restrict__ dis, const uint* __restrict__ hb,
                       const float* __restrict__ b1, float* __restrict__ agg) {
    const int t = threadIdx.x;
    const int v = blockIdx.x * 4 + (t >> 6);
    const int j = t & 63;
    const float dv = dis[v];
    uint pv = hb[(size_t)v * 64 + j];
    float ax = dv * bf2f(pv << 16 >> 16 << 16 >> 16 ? 0 : 0), ay;  // placeholder avoided below
    ax = dv * bf2f((pv & 0xffffu) << 0);  // low half
    ay = dv * bf2f(pv >> 16);
    // fix: bf2f expects the 16-bit value; low half is (pv & 0xffff)
    ax = dv * bf2f(pv & 0xffffu);
    float bx = 0.f, by = 0.f;
    int e = rowptr[v];
    const int end = rowptr[v + 1];
    for (; e + 2 <= end; e += 2) {
        int s0 = ssrc[e], s1 = ssrc[e + 1];
        float d0 = dis[s0], d1 = dis[s1];
        uint p0 = hb[(size_t)s0 * 64 + j];
        uint p1 = hb[(size_t)s1 * 64 + j];
        ax = fmaf(d0, bf2f(p0 & 0xffffu), ax);
        ay = fmaf(d0, bf2f(p0 >> 16), ay);
        bx = fmaf(d1, bf2f(p1 & 0xffffu), bx);
        by = fmaf(d1, bf2f(p1 >> 16), by);
    }
    if (e < end) {
        int s0 = ssrc[e];
        float d0 = dis[s0];
        uint p0 = hb[(size_t)s0 * 64 + j];
        ax = fmaf(d0, bf2f(p0 & 0xffffu), ax);
        ay = fmaf(d0, bf2f(p0 >> 16), ay);
    }
    float2 bb = ((const float2*)b1)[j];
    float2 o;
    o.x = fmaf(dv, ax + bx, bb.x);
    o.y = fmaf(dv, ay + by, bb.y);
    ((float2*)agg)[(size_t)v * 64 + j] = o;
}

// out[v] = b2 + dis[v]*( dis[v]*g[v] + sum dis[s]*g[s] ) ; wave/node, lane = 1 dim
__global__ void k_agg2(const int* __restrict__ rowptr, const int* __restrict__ ssrc,
                       const float* __restrict__ dis, const ushort* __restrict__ gb,
                       const float* __restrict__ b2, float* __restrict__ out) {
    const int t = threadIdx.x;
    const int v = blockIdx.x * 4 + (t >> 6);
    const int j = t & 63;
    const float dv = dis[v];
    float ax = dv * bf2f((uint)gb[(size_t)v * 64 + j]);
    float bx = 0.f;
    int e = rowptr[v];
    const int end = rowptr[v + 1];
    for (; e + 2 <= end; e += 2) {
        int s0 = ssrc[e], s1 = ssrc[e + 1];
        float d0 = dis[s0], d1 = dis[s1];
        float g0 = bf2f((uint)gb[(size_t)s0 * 64 + j]);
        float g1 = bf2f((uint)gb[(size_t)s1 * 64 + j]);
        ax = fmaf(d0, g0, ax);
        bx = fmaf(d1, g1, bx);
    }
    if (e < end) {
        int s0 = ssrc[e];
        ax = fmaf(dis[s0], bf2f((uint)gb[(size_t)s0 * 64 + j]), ax);
    }
    out[(size_t)v * 64 + j] = fmaf(dv, ax + bx, b2[j]);
}

// ---------------- launch ----------------

extern "C" void kernel_launch(void* const* d_in, const int* in_sizes, int n_in,
                              void* d_out, int out_size, void* d_ws, size_t ws_size,
                              hipStream_t stream) {
    const float* x  = (const float*)d_in[0];
    const float* W1 = (const float*)d_in[1];
    const float* b1 = (const float*)d_in[2];
    const float* W2 = (const float*)d_in[3];
    const float* b2 = (const float*)d_in[4];
    const int*   ei = (const int*)d_in[5];
    const int* src = ei;
    const int* dst = ei + EDGES;
    float* out = (float*)d_out;

    // workspace layout (bytes, all 16B-aligned)
    char* w = (char*)d_ws;
    int*    cnt    = (int*)w;                 w += 100000 * 4;
    int*    rowptr = (int*)w;                 w += 100004 * 4;
    int*    cursor = (int*)w;                 w += 100000 * 4;
    float*  dis    = (float*)w;               w += 100000 * 4;
    int*    bsums  = (int*)w;                 w += 128 * 4;
    int*    ssrc   = (int*)w;                 w += (size_t)EDGES * 4;
    ushort* hb     = (ushort*)w;              w += (size_t)NODES * 128 * 2;   // h bf16
    float*  buf2   = (float*)w;               w += (size_t)NODES * 128 * 4;   // agg1 f32
    ushort* gb     = (ushort*)w;              w += (size_t)NODES * 64 * 2;    // g bf16

    k_zero   <<<(NODES + 255) / 256, 256, 0, stream>>>(cnt);
    k_count  <<<(EDGES / 4 + 255) / 256, 256, 0, stream>>>(dst, cnt);
    k_scanA  <<<NBLK, 256, 0, stream>>>(cnt, bsums);
    k_scanB  <<<1, 128, 0, stream>>>(bsums);
    k_scanC  <<<NBLK, 256, 0, stream>>>(cnt, bsums, rowptr, cursor, dis);
    k_scatter<<<(EDGES / 4 + 255) / 256, 256, 0, stream>>>(src, dst, cursor, ssrc);

    k_gemm1  <<<NODES / 32, 256, 0, stream>>>(x, W1, hb);
    k_agg1   <<<NODES / 4, 256, 0, stream>>>(rowptr, ssrc, dis, (const uint*)hb, b1, buf2);
    k_gemm2  <<<NODES / 32, 256, 0, stream>>>(buf2, W2, gb);
    k_agg2   <<<NODES / 4, 256, 0, stream>>>(rowptr, ssrc, dis, gb, b2, out);
}

// Round 6
// 404.240 us; speedup vs baseline: 3.7204x; 1.4196x over previous
//
#include <hip/hip_runtime.h>

#define NODES 100000
#define EDGES 1600000
#define CHUNK 8192
#define NCH 196          // ceil(EDGES / CHUNK)
#define BSH 9            // bucket = dst >> 9  (512 nodes per bucket)
#define NBUCK 196        // ceil(NODES / 512)

typedef unsigned int uint;
typedef unsigned short ushort;

__device__ __forceinline__ float bf2f(uint u) {
    union { uint i; float f; } c; c.i = u << 16; return c.f;
}
__device__ __forceinline__ ushort f2bf(float f) {
    union { float f; uint i; } c; c.f = f;
    uint r = c.i + 0x7fff + ((c.i >> 16) & 1);   // round-to-nearest-even
    return (ushort)(r >> 16);
}

// ---------------- preprocessing: LDS-binned counting sort by dst ----------------

// per-chunk bucket histogram (LDS atomics only)
__global__ __launch_bounds__(256) void k_hist(const int* __restrict__ dst,
                                              int* __restrict__ hist) {
    __shared__ int h[NBUCK];
    const int t = threadIdx.x;
    if (t < NBUCK) h[t] = 0;
    __syncthreads();
    const int base = blockIdx.x * CHUNK;
    const int len = min(CHUNK, EDGES - base);
    for (int i = t; i < len; i += 256)
        atomicAdd(&h[dst[base + i] >> BSH], 1);
    __syncthreads();
    if (t < NBUCK) hist[blockIdx.x * NBUCK + t] = h[t];
}

// turn per-(chunk,bucket) counts into global base offsets; bucketStart; rowptr[N]
__global__ void k_offsets(int* __restrict__ hist, int* __restrict__ bucketStart,
                          int* __restrict__ rowptr) {
    __shared__ int tot[NBUCK];
    __shared__ int bstart[NBUCK + 1];
    const int t = threadIdx.x;   // 256 threads
    if (t < NBUCK) {
        int run = 0;
        for (int blk = 0; blk < NCH; ++blk) {
            int c = hist[blk * NBUCK + t];
            hist[blk * NBUCK + t] = run;   // per-bucket local prefix
            run += c;
        }
        tot[t] = run;
    }
    __syncthreads();
    if (t == 0) {
        int acc = 0;
        for (int b = 0; b < NBUCK; ++b) { bstart[b] = acc; acc += tot[b]; }
        bstart[NBUCK] = acc;               // == EDGES
        rowptr[NODES] = acc;
    }
    __syncthreads();
    if (t < NBUCK) {
        int bs = bstart[t];
        for (int blk = 0; blk < NCH; ++blk)
            hist[blk * NBUCK + t] += bs;
    }
    if (t <= NBUCK) bucketStart[t] = bstart[t];
}

// scatter edges into bucket-contiguous storage, packed (dstlocal<<17 | src)
__global__ __launch_bounds__(256) void k_bin(const int* __restrict__ src,
                                             const int* __restrict__ dst,
                                             const int* __restrict__ hist,
                                             uint* __restrict__ binned) {
    __shared__ int curs[NBUCK];
    const int t = threadIdx.x;
    if (t < NBUCK) curs[t] = hist[blockIdx.x * NBUCK + t];
    __syncthreads();
    const int base = blockIdx.x * CHUNK;
    const int len = min(CHUNK, EDGES - base);
    for (int i = t; i < len; i += 256) {
        int d = dst[base + i];
        int s = src[base + i];
        int pos = atomicAdd(&curs[d >> BSH], 1);
        binned[pos] = ((uint)(d & 511) << 17) | (uint)s;
    }
}

// per-bucket (512 nodes): count -> scan -> rowptr/dis/sorted ssrc
__global__ __launch_bounds__(256) void k_build(const uint* __restrict__ binned,
                                               const int* __restrict__ bucketStart,
                                               int* __restrict__ rowptr,
                                               float* __restrict__ dis,
                                               int* __restrict__ ssrc) {
    __shared__ int cnt[512];
    __shared__ int sh[256];
    const int t = threadIdx.x;
    const int b = blockIdx.x;
    const int eBase = bucketStart[b], eEnd = bucketStart[b + 1];
    const int nodeBase = b << BSH;
    const int nnode = min(512, NODES - nodeBase);
    cnt[t * 2] = 0; cnt[t * 2 + 1] = 0;
    __syncthreads();
    for (int i = eBase + t; i < eEnd; i += 256)
        atomicAdd(&cnt[binned[i] >> 17], 1);
    __syncthreads();
    const int c0 = cnt[t * 2], c1 = cnt[t * 2 + 1];
    const int sum = c0 + c1;
    sh[t] = sum; __syncthreads();
    for (int off = 1; off < 256; off <<= 1) {
        int add = (t >= off) ? sh[t - off] : 0;
        __syncthreads(); sh[t] += add; __syncthreads();
    }
    int excl = sh[t] - sum;
    const int ln0 = t * 2;
    if (ln0 < nnode) {
        rowptr[nodeBase + ln0] = eBase + excl;
        dis[nodeBase + ln0] = rsqrtf((float)(1 + c0));
    }
    int excl1 = excl + c0;
    if (ln0 + 1 < nnode) {
        rowptr[nodeBase + ln0 + 1] = eBase + excl1;
        dis[nodeBase + ln0 + 1] = rsqrtf((float)(1 + c1));
    }
    cnt[ln0] = excl; cnt[ln0 + 1] = excl1;
    __syncthreads();
    for (int i = eBase + t; i < eEnd; i += 256) {
        uint p = binned[i];
        int pos = atomicAdd(&cnt[p >> 17], 1);
        ssrc[eBase + pos] = (int)(p & 0x1FFFFu);
    }
}

// ---------------- GEMMs: W staged in LDS, bf16 outputs ----------------

// h = x @ W1  (32 rows/block, thread = 4 rows x 4 cols), out bf16
__global__ __launch_bounds__(256) void k_gemm1(const float* __restrict__ x,
                                               const float* __restrict__ W1,
                                               ushort* __restrict__ hb) {
    __shared__ float wsh[128 * 128];   // 64 KB
    __shared__ float xs[32 * 128];     // 16 KB
    const int t = threadIdx.x;
    {
        const float4* Wv = (const float4*)W1;
        float4* Sv = (float4*)wsh;
#pragma unroll
        for (int i = 0; i < 16; ++i) Sv[i * 256 + t] = Wv[i * 256 + t];
    }
    const int row0 = blockIdx.x * 32;
    {
        const float4* Xv = (const float4*)(x + (size_t)row0 * 128);
        float4* Sv = (float4*)xs;
#pragma unroll
        for (int i = 0; i < 4; ++i) Sv[i * 256 + t] = Xv[i * 256 + t];
    }
    __syncthreads();
    const int c4 = (t & 31) * 4;
    const int r0 = (t >> 5) * 4;
    float4 a0{0,0,0,0}, a1{0,0,0,0}, a2{0,0,0,0}, a3{0,0,0,0};
#pragma unroll 4
    for (int k = 0; k < 128; ++k) {
        float4 w = *(const float4*)&wsh[k * 128 + c4];
        float x0 = xs[(r0 + 0) * 128 + k];
        float x1 = xs[(r0 + 1) * 128 + k];
        float x2 = xs[(r0 + 2) * 128 + k];
        float x3 = xs[(r0 + 3) * 128 + k];
        a0.x = fmaf(x0, w.x, a0.x); a0.y = fmaf(x0, w.y, a0.y);
        a0.z = fmaf(x0, w.z, a0.z); a0.w = fmaf(x0, w.w, a0.w);
        a1.x = fmaf(x1, w.x, a1.x); a1.y = fmaf(x1, w.y, a1.y);
        a1.z = fmaf(x1, w.z, a1.z); a1.w = fmaf(x1, w.w, a1.w);
        a2.x = fmaf(x2, w.x, a2.x); a2.y = fmaf(x2, w.y, a2.y);
        a2.z = fmaf(x2, w.z, a2.z); a2.w = fmaf(x2, w.w, a2.w);
        a3.x = fmaf(x3, w.x, a3.x); a3.y = fmaf(x3, w.y, a3.y);
        a3.z = fmaf(x3, w.z, a3.z); a3.w = fmaf(x3, w.w, a3.w);
    }
    size_t base = (size_t)(row0 + r0) * 128 + c4;
    ushort4 u;
    u.x = f2bf(a0.x); u.y = f2bf(a0.y); u.z = f2bf(a0.z); u.w = f2bf(a0.w);
    *(ushort4*)&hb[base] = u;
    u.x = f2bf(a1.x); u.y = f2bf(a1.y); u.z = f2bf(a1.z); u.w = f2bf(a1.w);
    *(ushort4*)&hb[base + 128] = u;
    u.x = f2bf(a2.x); u.y = f2bf(a2.y); u.z = f2bf(a2.z); u.w = f2bf(a2.w);
    *(ushort4*)&hb[base + 256] = u;
    u.x = f2bf(a3.x); u.y = f2bf(a3.y); u.z = f2bf(a3.z); u.w = f2bf(a3.w);
    *(ushort4*)&hb[base + 384] = u;
}

// g = ab(bf16, relu'd) @ W2 ; 32 rows/block, thread = 2 rows x 4 cols, out bf16
__global__ __launch_bounds__(256) void k_gemm2(const uint* __restrict__ ab,
                                               const float* __restrict__ W2,
                                               ushort* __restrict__ gb) {
    __shared__ float wsh[128 * 64];    // 32 KB
    __shared__ float xs[32 * 132];     // padded stride 132
    const int t = threadIdx.x;
    {
        const float4* Wv = (const float4*)W2;
        float4* Sv = (float4*)wsh;
#pragma unroll
        for (int i = 0; i < 8; ++i) Sv[i * 256 + t] = Wv[i * 256 + t];
    }
    const int row0 = blockIdx.x * 32;
    {
        const uint4* Xv = (const uint4*)(ab + (size_t)row0 * 64);  // 8 bf16 per uint4
#pragma unroll
        for (int i = 0; i < 2; ++i) {
            int f = i * 256 + t;               // uint4 index; flat elem = f*8
            uint4 vv = Xv[f];
            int row = f >> 4, col = (f & 15) * 8;
            float* d = &xs[row * 132 + col];
            d[0] = bf2f(vv.x & 0xffffu); d[1] = bf2f(vv.x >> 16);
            d[2] = bf2f(vv.y & 0xffffu); d[3] = bf2f(vv.y >> 16);
            d[4] = bf2f(vv.z & 0xffffu); d[5] = bf2f(vv.z >> 16);
            d[6] = bf2f(vv.w & 0xffffu); d[7] = bf2f(vv.w >> 16);
        }
    }
    __syncthreads();
    const int c4 = (t & 15) * 4;
    const int r0 = (t >> 4) * 2;
    float4 a0{0,0,0,0}, a1{0,0,0,0};
#pragma unroll 4
    for (int k = 0; k < 128; ++k) {
        float4 w = *(const float4*)&wsh[k * 64 + c4];
        float x0 = xs[(r0 + 0) * 132 + k];
        float x1 = xs[(r0 + 1) * 132 + k];
        a0.x = fmaf(x0, w.x, a0.x); a0.y = fmaf(x0, w.y, a0.y);
        a0.z = fmaf(x0, w.z, a0.z); a0.w = fmaf(x0, w.w, a0.w);
        a1.x = fmaf(x1, w.x, a1.x); a1.y = fmaf(x1, w.y, a1.y);
        a1.z = fmaf(x1, w.z, a1.z); a1.w = fmaf(x1, w.w, a1.w);
    }
    size_t base = (size_t)(row0 + r0) * 64 + c4;
    ushort4 u;
    u.x = f2bf(a0.x); u.y = f2bf(a0.y); u.z = f2bf(a0.z); u.w = f2bf(a0.w);
    *(ushort4*)&gb[base] = u;
    u.x = f2bf(a1.x); u.y = f2bf(a1.y); u.z = f2bf(a1.z); u.w = f2bf(a1.w);
    *(ushort4*)&gb[base + 64] = u;
}

// ---------------- CSR aggregation (shfl-batched, bf16 gathers, f32 accumulate) ----

// ab[v] = relu( b1 + dis[v]*( dis[v]*h[v] + sum dis[s]*h[s] ) ) as bf16
// wave/node, lane = 2 dims (one uint of hb)
__global__ void k_agg1(const int* __restrict__ rowptr, const int* __restrict__ ssrc,
                       const float* __restrict__ dis, const uint* __restrict__ hb,
                       const float* __restrict__ b1, uint* __restrict__ ab) {
    const int t = threadIdx.x;
    const int v = blockIdx.x * 4 + (t >> 6);
    const int j = t & 63;
    const float dv = dis[v];
    uint pv = hb[(size_t)v * 64 + j];
    float ax = dv * bf2f(pv & 0xffffu);
    float ay = dv * bf2f(pv >> 16);
    float bx = 0.f, by = 0.f;
    int e = rowptr[v];
    const int end = rowptr[v + 1];
    while (e < end) {
        int m = end - e; if (m > 64) m = 64;
        int s = 0; float dsv = 0.f;
        if (j < m) { s = ssrc[e + j]; dsv = dis[s]; }
        int i = 0;
        for (; i + 2 <= m; i += 2) {
            int s0 = __shfl(s, i), s1 = __shfl(s, i + 1);
            float d0 = __shfl(dsv, i), d1 = __shfl(dsv, i + 1);
            uint p0 = hb[(size_t)s0 * 64 + j];
            uint p1 = hb[(size_t)s1 * 64 + j];
            ax = fmaf(d0, bf2f(p0 & 0xffffu), ax);
            ay = fmaf(d0, bf2f(p0 >> 16), ay);
            bx = fmaf(d1, bf2f(p1 & 0xffffu), bx);
            by = fmaf(d1, bf2f(p1 >> 16), by);
        }
        if (i < m) {
            int s0 = __shfl(s, i); float d0 = __shfl(dsv, i);
            uint p0 = hb[(size_t)s0 * 64 + j];
            ax = fmaf(d0, bf2f(p0 & 0xffffu), ax);
            ay = fmaf(d0, bf2f(p0 >> 16), ay);
        }
        e += m;
    }
    float2 bb = ((const float2*)b1)[j];
    float ox = fmaxf(fmaf(dv, ax + bx, bb.x), 0.f);
    float oy = fmaxf(fmaf(dv, ay + by, bb.y), 0.f);
    ab[(size_t)v * 64 + j] = ((uint)f2bf(oy) << 16) | (uint)f2bf(ox);
}

// out[v] = b2 + dis[v]*( dis[v]*g[v] + sum dis[s]*g[s] ) ; wave/node, lane = 1 dim
__global__ void k_agg2(const int* __restrict__ rowptr, const int* __restrict__ ssrc,
                       const float* __restrict__ dis, const ushort* __restrict__ gb,
                       const float* __restrict__ b2, float* __restrict__ out) {
    const int t = threadIdx.x;
    const int v = blockIdx.x * 4 + (t >> 6);
    const int j = t & 63;
    const float dv = dis[v];
    float ax = dv * bf2f((uint)gb[(size_t)v * 64 + j]);
    float bx = 0.f;
    int e = rowptr[v];
    const int end = rowptr[v + 1];
    while (e < end) {
        int m = end - e; if (m > 64) m = 64;
        int s = 0; float dsv = 0.f;
        if (j < m) { s = ssrc[e + j]; dsv = dis[s]; }
        int i = 0;
        for (; i + 2 <= m; i += 2) {
            int s0 = __shfl(s, i), s1 = __shfl(s, i + 1);
            float d0 = __shfl(dsv, i), d1 = __shfl(dsv, i + 1);
            float g0 = bf2f((uint)gb[(size_t)s0 * 64 + j]);
            float g1 = bf2f((uint)gb[(size_t)s1 * 64 + j]);
            ax = fmaf(d0, g0, ax);
            bx = fmaf(d1, g1, bx);
        }
        if (i < m) {
            int s0 = __shfl(s, i); float d0 = __shfl(dsv, i);
            ax = fmaf(d0, bf2f((uint)gb[(size_t)s0 * 64 + j]), ax);
        }
        e += m;
    }
    out[(size_t)v * 64 + j] = fmaf(dv, ax + bx, b2[j]);
}

// ---------------- launch ----------------

extern "C" void kernel_launch(void* const* d_in, const int* in_sizes, int n_in,
                              void* d_out, int out_size, void* d_ws, size_t ws_size,
                              hipStream_t stream) {
    const float* x  = (const float*)d_in[0];
    const float* W1 = (const float*)d_in[1];
    const float* b1 = (const float*)d_in[2];
    const float* W2 = (const float*)d_in[3];
    const float* b2 = (const float*)d_in[4];
    const int*   ei = (const int*)d_in[5];
    const int* src = ei;
    const int* dst = ei + EDGES;
    float* out = (float*)d_out;

    char* w = (char*)d_ws;
    int*    hist   = (int*)w;    w += (size_t)NCH * NBUCK * 4 + 256;  // pad
    int*    bstart = (int*)w;    w += 256 * 4;
    int*    rowptr = (int*)w;    w += 100004 * 4;
    float*  dis    = (float*)w;  w += 100000 * 4;
    uint*   binned = (uint*)w;   w += (size_t)EDGES * 4;
    int*    ssrc   = (int*)w;    w += (size_t)EDGES * 4;
    ushort* hb     = (ushort*)w; w += (size_t)NODES * 128 * 2;
    uint*   ab     = (uint*)w;   w += (size_t)NODES * 64 * 4;
    ushort* gb     = (ushort*)w; w += (size_t)NODES * 64 * 2;

    k_hist   <<<NCH, 256, 0, stream>>>(dst, hist);
    k_offsets<<<1, 256, 0, stream>>>(hist, bstart, rowptr);
    k_bin    <<<NCH, 256, 0, stream>>>(src, dst, hist, binned);
    k_build  <<<NBUCK, 256, 0, stream>>>(binned, bstart, rowptr, dis, ssrc);

    k_gemm1  <<<NODES / 32, 256, 0, stream>>>(x, W1, hb);
    k_agg1   <<<NODES / 4, 256, 0, stream>>>(rowptr, ssrc, dis, (const uint*)hb, b1, ab);
    k_gemm2  <<<NODES / 32, 256, 0, stream>>>(ab, W2, gb);
    k_agg2   <<<NODES / 4, 256, 0, stream>>>(rowptr, ssrc, dis, gb, b2, out);
}

// Round 7
// 397.619 us; speedup vs baseline: 3.7824x; 1.0167x over previous
//
#include <hip/hip_runtime.h>

#define NODES 100000
#define EDGES 1600000
#define CHUNK 8192
#define NCH 196          // ceil(EDGES / CHUNK)
#define BSH 9            // bucket = dst >> 9  (512 nodes per bucket)
#define NBUCK 196        // ceil(NODES / 512)

typedef unsigned int uint;
typedef unsigned short ushort;

__device__ __forceinline__ float bf2f(uint u) {
    union { uint i; float f; } c; c.i = u << 16; return c.f;
}
__device__ __forceinline__ ushort f2bf(float f) {
    union { float f; uint i; } c; c.f = f;
    uint r = c.i + 0x7fff + ((c.i >> 16) & 1);   // round-to-nearest-even
    return (ushort)(r >> 16);
}

// ---------------- preprocessing: LDS-binned counting sort by dst ----------------

__global__ __launch_bounds__(256) void k_hist(const int* __restrict__ dst,
                                              int* __restrict__ hist) {
    __shared__ int h[NBUCK];
    const int t = threadIdx.x;
    if (t < NBUCK) h[t] = 0;
    __syncthreads();
    const int base = blockIdx.x * CHUNK;
    const int len = min(CHUNK, EDGES - base);
    for (int i = t; i < len; i += 256)
        atomicAdd(&h[dst[base + i] >> BSH], 1);
    __syncthreads();
    if (t < NBUCK) hist[blockIdx.x * NBUCK + t] = h[t];
}

__global__ void k_offsets(int* __restrict__ hist, int* __restrict__ bucketStart,
                          int* __restrict__ rowptr) {
    __shared__ int tot[NBUCK];
    __shared__ int bstart[NBUCK + 1];
    const int t = threadIdx.x;   // 256 threads
    if (t < NBUCK) {
        int run = 0;
        for (int blk = 0; blk < NCH; ++blk) {
            int c = hist[blk * NBUCK + t];
            hist[blk * NBUCK + t] = run;   // per-bucket local prefix
            run += c;
        }
        tot[t] = run;
    }
    __syncthreads();
    if (t == 0) {
        int acc = 0;
        for (int b = 0; b < NBUCK; ++b) { bstart[b] = acc; acc += tot[b]; }
        bstart[NBUCK] = acc;               // == EDGES
        rowptr[NODES] = acc;
    }
    __syncthreads();
    if (t < NBUCK) {
        int bs = bstart[t];
        for (int blk = 0; blk < NCH; ++blk)
            hist[blk * NBUCK + t] += bs;
    }
    if (t <= NBUCK) bucketStart[t] = bstart[t];
}

__global__ __launch_bounds__(256) void k_bin(const int* __restrict__ src,
                                             const int* __restrict__ dst,
                                             const int* __restrict__ hist,
                                             uint* __restrict__ binned) {
    __shared__ int curs[NBUCK];
    const int t = threadIdx.x;
    if (t < NBUCK) curs[t] = hist[blockIdx.x * NBUCK + t];
    __syncthreads();
    const int base = blockIdx.x * CHUNK;
    const int len = min(CHUNK, EDGES - base);
    for (int i = t; i < len; i += 256) {
        int d = dst[base + i];
        int s = src[base + i];
        int pos = atomicAdd(&curs[d >> BSH], 1);
        binned[pos] = ((uint)(d & 511) << 17) | (uint)s;
    }
}

__global__ __launch_bounds__(256) void k_build(const uint* __restrict__ binned,
                                               const int* __restrict__ bucketStart,
                                               int* __restrict__ rowptr,
                                               float* __restrict__ dis,
                                               int* __restrict__ ssrc) {
    __shared__ int cnt[512];
    __shared__ int sh[256];
    const int t = threadIdx.x;
    const int b = blockIdx.x;
    const int eBase = bucketStart[b], eEnd = bucketStart[b + 1];
    const int nodeBase = b << BSH;
    const int nnode = min(512, NODES - nodeBase);
    cnt[t * 2] = 0; cnt[t * 2 + 1] = 0;
    __syncthreads();
    for (int i = eBase + t; i < eEnd; i += 256)
        atomicAdd(&cnt[binned[i] >> 17], 1);
    __syncthreads();
    const int c0 = cnt[t * 2], c1 = cnt[t * 2 + 1];
    const int sum = c0 + c1;
    sh[t] = sum; __syncthreads();
    for (int off = 1; off < 256; off <<= 1) {
        int add = (t >= off) ? sh[t - off] : 0;
        __syncthreads(); sh[t] += add; __syncthreads();
    }
    int excl = sh[t] - sum;
    const int ln0 = t * 2;
    if (ln0 < nnode) {
        rowptr[nodeBase + ln0] = eBase + excl;
        dis[nodeBase + ln0] = rsqrtf((float)(1 + c0));
    }
    int excl1 = excl + c0;
    if (ln0 + 1 < nnode) {
        rowptr[nodeBase + ln0 + 1] = eBase + excl1;
        dis[nodeBase + ln0 + 1] = rsqrtf((float)(1 + c1));
    }
    cnt[ln0] = excl; cnt[ln0 + 1] = excl1;
    __syncthreads();
    for (int i = eBase + t; i < eEnd; i += 256) {
        uint p = binned[i];
        int pos = atomicAdd(&cnt[p >> 17], 1);
        ssrc[eBase + pos] = (int)(p & 0x1FFFFu);
    }
}

// ---------------- GEMMs: W staged in LDS, dis-scaled bf16 outputs ----------------

// hb'[row] = bf16( dis[row] * (x @ W1)[row] )  (32 rows/block, thread = 4r x 4c)
__global__ __launch_bounds__(256) void k_gemm1(const float* __restrict__ x,
                                               const float* __restrict__ W1,
                                               const float* __restrict__ dis,
                                               ushort* __restrict__ hb) {
    __shared__ float wsh[128 * 128];   // 64 KB
    __shared__ float xs[32 * 128];     // 16 KB
    const int t = threadIdx.x;
    {
        const float4* Wv = (const float4*)W1;
        float4* Sv = (float4*)wsh;
#pragma unroll
        for (int i = 0; i < 16; ++i) Sv[i * 256 + t] = Wv[i * 256 + t];
    }
    const int row0 = blockIdx.x * 32;
    {
        const float4* Xv = (const float4*)(x + (size_t)row0 * 128);
        float4* Sv = (float4*)xs;
#pragma unroll
        for (int i = 0; i < 4; ++i) Sv[i * 256 + t] = Xv[i * 256 + t];
    }
    __syncthreads();
    const int c4 = (t & 31) * 4;
    const int r0 = (t >> 5) * 4;
    float4 a0{0,0,0,0}, a1{0,0,0,0}, a2{0,0,0,0}, a3{0,0,0,0};
#pragma unroll 4
    for (int k = 0; k < 128; ++k) {
        float4 w = *(const float4*)&wsh[k * 128 + c4];
        float x0 = xs[(r0 + 0) * 128 + k];
        float x1 = xs[(r0 + 1) * 128 + k];
        float x2 = xs[(r0 + 2) * 128 + k];
        float x3 = xs[(r0 + 3) * 128 + k];
        a0.x = fmaf(x0, w.x, a0.x); a0.y = fmaf(x0, w.y, a0.y);
        a0.z = fmaf(x0, w.z, a0.z); a0.w = fmaf(x0, w.w, a0.w);
        a1.x = fmaf(x1, w.x, a1.x); a1.y = fmaf(x1, w.y, a1.y);
        a1.z = fmaf(x1, w.z, a1.z); a1.w = fmaf(x1, w.w, a1.w);
        a2.x = fmaf(x2, w.x, a2.x); a2.y = fmaf(x2, w.y, a2.y);
        a2.z = fmaf(x2, w.z, a2.z); a2.w = fmaf(x2, w.w, a2.w);
        a3.x = fmaf(x3, w.x, a3.x); a3.y = fmaf(x3, w.y, a3.y);
        a3.z = fmaf(x3, w.z, a3.z); a3.w = fmaf(x3, w.w, a3.w);
    }
    const float d0 = dis[row0 + r0], d1 = dis[row0 + r0 + 1];
    const float d2 = dis[row0 + r0 + 2], d3 = dis[row0 + r0 + 3];
    size_t base = (size_t)(row0 + r0) * 128 + c4;
    ushort4 u;
    u.x = f2bf(a0.x * d0); u.y = f2bf(a0.y * d0); u.z = f2bf(a0.z * d0); u.w = f2bf(a0.w * d0);
    *(ushort4*)&hb[base] = u;
    u.x = f2bf(a1.x * d1); u.y = f2bf(a1.y * d1); u.z = f2bf(a1.z * d1); u.w = f2bf(a1.w * d1);
    *(ushort4*)&hb[base + 128] = u;
    u.x = f2bf(a2.x * d2); u.y = f2bf(a2.y * d2); u.z = f2bf(a2.z * d2); u.w = f2bf(a2.w * d2);
    *(ushort4*)&hb[base + 256] = u;
    u.x = f2bf(a3.x * d3); u.y = f2bf(a3.y * d3); u.z = f2bf(a3.z * d3); u.w = f2bf(a3.w * d3);
    *(ushort4*)&hb[base + 384] = u;
}

// gb'[row] = bf16( dis[row] * (ab @ W2)[row] ) ; ab = relu'd bf16 (32 rows/block)
__global__ __launch_bounds__(256) void k_gemm2(const uint* __restrict__ ab,
                                               const float* __restrict__ W2,
                                               const float* __restrict__ dis,
                                               ushort* __restrict__ gb) {
    __shared__ float wsh[128 * 64];    // 32 KB
    __shared__ float xs[32 * 132];     // padded stride 132
    const int t = threadIdx.x;
    {
        const float4* Wv = (const float4*)W2;
        float4* Sv = (float4*)wsh;
#pragma unroll
        for (int i = 0; i < 8; ++i) Sv[i * 256 + t] = Wv[i * 256 + t];
    }
    const int row0 = blockIdx.x * 32;
    {
        const uint4* Xv = (const uint4*)(ab + (size_t)row0 * 64);  // 8 bf16 per uint4
#pragma unroll
        for (int i = 0; i < 2; ++i) {
            int f = i * 256 + t;               // uint4 index; flat elem = f*8
            uint4 vv = Xv[f];
            int row = f >> 4, col = (f & 15) * 8;
            float* d = &xs[row * 132 + col];
            d[0] = bf2f(vv.x & 0xffffu); d[1] = bf2f(vv.x >> 16);
            d[2] = bf2f(vv.y & 0xffffu); d[3] = bf2f(vv.y >> 16);
            d[4] = bf2f(vv.z & 0xffffu); d[5] = bf2f(vv.z >> 16);
            d[6] = bf2f(vv.w & 0xffffu); d[7] = bf2f(vv.w >> 16);
        }
    }
    __syncthreads();
    const int c4 = (t & 15) * 4;
    const int r0 = (t >> 4) * 2;
    float4 a0{0,0,0,0}, a1{0,0,0,0};
#pragma unroll 4
    for (int k = 0; k < 128; ++k) {
        float4 w = *(const float4*)&wsh[k * 64 + c4];
        float x0 = xs[(r0 + 0) * 132 + k];
        float x1 = xs[(r0 + 1) * 132 + k];
        a0.x = fmaf(x0, w.x, a0.x); a0.y = fmaf(x0, w.y, a0.y);
        a0.z = fmaf(x0, w.z, a0.z); a0.w = fmaf(x0, w.w, a0.w);
        a1.x = fmaf(x1, w.x, a1.x); a1.y = fmaf(x1, w.y, a1.y);
        a1.z = fmaf(x1, w.z, a1.z); a1.w = fmaf(x1, w.w, a1.w);
    }
    const float d0 = dis[row0 + r0], d1 = dis[row0 + r0 + 1];
    size_t base = (size_t)(row0 + r0) * 64 + c4;
    ushort4 u;
    u.x = f2bf(a0.x * d0); u.y = f2bf(a0.y * d0); u.z = f2bf(a0.z * d0); u.w = f2bf(a0.w * d0);
    *(ushort4*)&gb[base] = u;
    u.x = f2bf(a1.x * d1); u.y = f2bf(a1.y * d1); u.z = f2bf(a1.z * d1); u.w = f2bf(a1.w * d1);
    *(ushort4*)&gb[base + 64] = u;
}

// ---------------- CSR aggregation: 2 edges/wave, uint2/uint gathers, no per-edge dis

// ab[v] = relu( b1 + dis[v] * ( hb'[v] + sum_{s in N(v)} hb'[s] ) )  as bf16
// wave/node; half = lane>=32; lane q holds dims 4q..4q+3 (uint2 of the row)
__global__ void k_agg1(const int* __restrict__ rowptr, const int* __restrict__ ssrc,
                       const float* __restrict__ dis, const uint2* __restrict__ hb2,
                       const float* __restrict__ b1, uint2* __restrict__ ab2) {
    const int t = threadIdx.x;
    const int v = blockIdx.x * 4 + (t >> 6);
    const int lane = t & 63;
    const int half = lane >> 5;
    const int q = lane & 31;
    float4 accA = {0.f, 0.f, 0.f, 0.f}, accB = {0.f, 0.f, 0.f, 0.f};
    if (half == 0) {
        uint2 pv = hb2[(size_t)v * 32 + q];
        accA.x = bf2f(pv.x & 0xffffu); accA.y = bf2f(pv.x >> 16);
        accA.z = bf2f(pv.y & 0xffffu); accA.w = bf2f(pv.y >> 16);
    }
    int e = rowptr[v];
    const int end = rowptr[v + 1];
    while (e < end) {
        int m = end - e; if (m > 64) m = 64;
        int s = (lane < m) ? ssrc[e + lane] : 0;
        int i = 0;
        for (; i + 4 <= m; i += 4) {
            int s0 = __shfl(s, i + half);
            int s1 = __shfl(s, i + 2 + half);
            uint2 p0 = hb2[(size_t)s0 * 32 + q];
            uint2 p1 = hb2[(size_t)s1 * 32 + q];
            accA.x += bf2f(p0.x & 0xffffu); accA.y += bf2f(p0.x >> 16);
            accA.z += bf2f(p0.y & 0xffffu); accA.w += bf2f(p0.y >> 16);
            accB.x += bf2f(p1.x & 0xffffu); accB.y += bf2f(p1.x >> 16);
            accB.z += bf2f(p1.y & 0xffffu); accB.w += bf2f(p1.y >> 16);
        }
        if (i + 2 <= m) {
            int s0 = __shfl(s, i + half);
            uint2 p0 = hb2[(size_t)s0 * 32 + q];
            accA.x += bf2f(p0.x & 0xffffu); accA.y += bf2f(p0.x >> 16);
            accA.z += bf2f(p0.y & 0xffffu); accA.w += bf2f(p0.y >> 16);
            i += 2;
        }
        if (i < m) {
            int s0 = __shfl(s, i);
            uint2 p0 = hb2[(size_t)s0 * 32 + q];
            if (half == 0) {
                accA.x += bf2f(p0.x & 0xffffu); accA.y += bf2f(p0.x >> 16);
                accA.z += bf2f(p0.y & 0xffffu); accA.w += bf2f(p0.y >> 16);
            }
        }
        e += m;
    }
    float4 tot;
    tot.x = accA.x + accB.x; tot.y = accA.y + accB.y;
    tot.z = accA.z + accB.z; tot.w = accA.w + accB.w;
    tot.x += __shfl_xor(tot.x, 32); tot.y += __shfl_xor(tot.y, 32);
    tot.z += __shfl_xor(tot.z, 32); tot.w += __shfl_xor(tot.w, 32);
    if (half == 0) {
        const float dv = dis[v];
        const float4 bb = ((const float4*)b1)[q];
        float ox = fmaxf(fmaf(dv, tot.x, bb.x), 0.f);
        float oy = fmaxf(fmaf(dv, tot.y, bb.y), 0.f);
        float oz = fmaxf(fmaf(dv, tot.z, bb.z), 0.f);
        float ow = fmaxf(fmaf(dv, tot.w, bb.w), 0.f);
        uint2 o;
        o.x = ((uint)f2bf(oy) << 16) | (uint)f2bf(ox);
        o.y = ((uint)f2bf(ow) << 16) | (uint)f2bf(oz);
        ab2[(size_t)v * 32 + q] = o;
    }
}

// out[v] = b2 + dis[v] * ( gb'[v] + sum gb'[s] ) ; lane q holds dims 2q,2q+1
__global__ void k_agg2(const int* __restrict__ rowptr, const int* __restrict__ ssrc,
                       const float* __restrict__ dis, const uint* __restrict__ gbu,
                       const float* __restrict__ b2, float* __restrict__ out) {
    const int t = threadIdx.x;
    const int v = blockIdx.x * 4 + (t >> 6);
    const int lane = t & 63;
    const int half = lane >> 5;
    const int q = lane & 31;
    float2 accA = {0.f, 0.f}, accB = {0.f, 0.f};
    if (half == 0) {
        uint pv = gbu[(size_t)v * 32 + q];
        accA.x = bf2f(pv & 0xffffu); accA.y = bf2f(pv >> 16);
    }
    int e = rowptr[v];
    const int end = rowptr[v + 1];
    while (e < end) {
        int m = end - e; if (m > 64) m = 64;
        int s = (lane < m) ? ssrc[e + lane] : 0;
        int i = 0;
        for (; i + 4 <= m; i += 4) {
            int s0 = __shfl(s, i + half);
            int s1 = __shfl(s, i + 2 + half);
            uint p0 = gbu[(size_t)s0 * 32 + q];
            uint p1 = gbu[(size_t)s1 * 32 + q];
            accA.x += bf2f(p0 & 0xffffu); accA.y += bf2f(p0 >> 16);
            accB.x += bf2f(p1 & 0xffffu); accB.y += bf2f(p1 >> 16);
        }
        if (i + 2 <= m) {
            int s0 = __shfl(s, i + half);
            uint p0 = gbu[(size_t)s0 * 32 + q];
            accA.x += bf2f(p0 & 0xffffu); accA.y += bf2f(p0 >> 16);
            i += 2;
        }
        if (i < m) {
            int s0 = __shfl(s, i);
            uint p0 = gbu[(size_t)s0 * 32 + q];
            if (half == 0) {
                accA.x += bf2f(p0 & 0xffffu); accA.y += bf2f(p0 >> 16);
            }
        }
        e += m;
    }
    float2 tot;
    tot.x = accA.x + accB.x; tot.y = accA.y + accB.y;
    tot.x += __shfl_xor(tot.x, 32);
    tot.y += __shfl_xor(tot.y, 32);
    if (half == 0) {
        const float dv = dis[v];
        const float2 bb = ((const float2*)b2)[q];
        float2 o;
        o.x = fmaf(dv, tot.x, bb.x);
        o.y = fmaf(dv, tot.y, bb.y);
        ((float2*)out)[(size_t)v * 32 + q] = o;
    }
}

// ---------------- launch ----------------

extern "C" void kernel_launch(void* const* d_in, const int* in_sizes, int n_in,
                              void* d_out, int out_size, void* d_ws, size_t ws_size,
                              hipStream_t stream) {
    const float* x  = (const float*)d_in[0];
    const float* W1 = (const float*)d_in[1];
    const float* b1 = (const float*)d_in[2];
    const float* W2 = (const float*)d_in[3];
    const float* b2 = (const float*)d_in[4];
    const int*   ei = (const int*)d_in[5];
    const int* src = ei;
    const int* dst = ei + EDGES;
    float* out = (float*)d_out;

    char* w = (char*)d_ws;
    int*    hist   = (int*)w;    w += (size_t)NCH * NBUCK * 4 + 256;  // pad
    int*    bstart = (int*)w;    w += 256 * 4;
    int*    rowptr = (int*)w;    w += 100004 * 4;
    float*  dis    = (float*)w;  w += 100000 * 4 + 16;
    uint*   binned = (uint*)w;   w += (size_t)EDGES * 4;
    int*    ssrc   = (int*)w;    w += (size_t)EDGES * 4;
    ushort* hb     = (ushort*)w; w += (size_t)NODES * 128 * 2;
    uint*   ab     = (uint*)w;   w += (size_t)NODES * 64 * 4;
    ushort* gb     = (ushort*)w; w += (size_t)NODES * 64 * 2;

    k_hist   <<<NCH, 256, 0, stream>>>(dst, hist);
    k_offsets<<<1, 256, 0, stream>>>(hist, bstart, rowptr);
    k_bin    <<<NCH, 256, 0, stream>>>(src, dst, hist, binned);
    k_build  <<<NBUCK, 256, 0, stream>>>(binned, bstart, rowptr, dis, ssrc);

    k_gemm1  <<<NODES / 32, 256, 0, stream>>>(x, W1, dis, hb);
    k_agg1   <<<NODES / 4, 256, 0, stream>>>(rowptr, ssrc, dis, (const uint2*)hb, b1, (uint2*)ab);
    k_gemm2  <<<NODES / 32, 256, 0, stream>>>(ab, W2, dis, gb);
    k_agg2   <<<NODES / 4, 256, 0, stream>>>(rowptr, ssrc, dis, (const uint*)gb, b2, out);
}

// Round 8
// 386.038 us; speedup vs baseline: 3.8959x; 1.0300x over previous
//
#include <hip/hip_runtime.h>

#define NODES 100000
#define EDGES 1600000
#define CHUNK 8192
#define NCH 196          // ceil(EDGES / CHUNK)
#define BSH 9            // bucket = dst >> 9  (512 nodes per bucket)
#define NBUCK 196        // ceil(NODES / 512)

typedef unsigned int uint;
typedef unsigned short ushort;

__device__ __forceinline__ float bf2f(uint u) {
    union { uint i; float f; } c; c.i = u << 16; return c.f;
}
__device__ __forceinline__ ushort f2bf(float f) {
    union { float f; uint i; } c; c.f = f;
    uint r = c.i + 0x7fff + ((c.i >> 16) & 1);   // round-to-nearest-even
    return (ushort)(r >> 16);
}

// ---------------- preprocessing: LDS-binned counting sort by dst ----------------

__global__ __launch_bounds__(256) void k_hist(const int* __restrict__ dst,
                                              int* __restrict__ hist) {
    __shared__ int h[NBUCK];
    const int t = threadIdx.x;
    if (t < NBUCK) h[t] = 0;
    __syncthreads();
    const int base = blockIdx.x * CHUNK;
    const int len = min(CHUNK, EDGES - base);
    for (int i = t; i < len; i += 256)
        atomicAdd(&h[dst[base + i] >> BSH], 1);
    __syncthreads();
    if (t < NBUCK) hist[blockIdx.x * NBUCK + t] = h[t];
}

__global__ void k_offsets(int* __restrict__ hist, int* __restrict__ bucketStart,
                          int* __restrict__ rowptr) {
    __shared__ int tot[NBUCK];
    __shared__ int bstart[NBUCK + 1];
    const int t = threadIdx.x;   // 256 threads
    if (t < NBUCK) {
        int run = 0;
        for (int blk = 0; blk < NCH; ++blk) {
            int c = hist[blk * NBUCK + t];
            hist[blk * NBUCK + t] = run;   // per-bucket local prefix
            run += c;
        }
        tot[t] = run;
    }
    __syncthreads();
    if (t == 0) {
        int acc = 0;
        for (int b = 0; b < NBUCK; ++b) { bstart[b] = acc; acc += tot[b]; }
        bstart[NBUCK] = acc;               // == EDGES
        rowptr[NODES] = acc;
    }
    __syncthreads();
    if (t < NBUCK) {
        int bs = bstart[t];
        for (int blk = 0; blk < NCH; ++blk)
            hist[blk * NBUCK + t] += bs;
    }
    if (t <= NBUCK) bucketStart[t] = bstart[t];
}

__global__ __launch_bounds__(256) void k_bin(const int* __restrict__ src,
                                             const int* __restrict__ dst,
                                             const int* __restrict__ hist,
                                             uint* __restrict__ binned) {
    __shared__ int curs[NBUCK];
    const int t = threadIdx.x;
    if (t < NBUCK) curs[t] = hist[blockIdx.x * NBUCK + t];
    __syncthreads();
    const int base = blockIdx.x * CHUNK;
    const int len = min(CHUNK, EDGES - base);
    for (int i = t; i < len; i += 256) {
        int d = dst[base + i];
        int s = src[base + i];
        int pos = atomicAdd(&curs[d >> BSH], 1);
        binned[pos] = ((uint)(d & 511) << 17) | (uint)s;
    }
}

__global__ __launch_bounds__(256) void k_build(const uint* __restrict__ binned,
                                               const int* __restrict__ bucketStart,
                                               int* __restrict__ rowptr,
                                               float* __restrict__ dis,
                                               int* __restrict__ ssrc) {
    __shared__ int cnt[512];
    __shared__ int sh[256];
    const int t = threadIdx.x;
    const int b = blockIdx.x;
    const int eBase = bucketStart[b], eEnd = bucketStart[b + 1];
    const int nodeBase = b << BSH;
    const int nnode = min(512, NODES - nodeBase);
    cnt[t * 2] = 0; cnt[t * 2 + 1] = 0;
    __syncthreads();
    for (int i = eBase + t; i < eEnd; i += 256)
        atomicAdd(&cnt[binned[i] >> 17], 1);
    __syncthreads();
    const int c0 = cnt[t * 2], c1 = cnt[t * 2 + 1];
    const int sum = c0 + c1;
    sh[t] = sum; __syncthreads();
    for (int off = 1; off < 256; off <<= 1) {
        int add = (t >= off) ? sh[t - off] : 0;
        __syncthreads(); sh[t] += add; __syncthreads();
    }
    int excl = sh[t] - sum;
    const int ln0 = t * 2;
    if (ln0 < nnode) {
        rowptr[nodeBase + ln0] = eBase + excl;
        dis[nodeBase + ln0] = rsqrtf((float)(1 + c0));
    }
    int excl1 = excl + c0;
    if (ln0 + 1 < nnode) {
        rowptr[nodeBase + ln0 + 1] = eBase + excl1;
        dis[nodeBase + ln0 + 1] = rsqrtf((float)(1 + c1));
    }
    cnt[ln0] = excl; cnt[ln0 + 1] = excl1;
    __syncthreads();
    for (int i = eBase + t; i < eEnd; i += 256) {
        uint p = binned[i];
        int pos = atomicAdd(&cnt[p >> 17], 1);
        ssrc[eBase + pos] = (int)(p & 0x1FFFFu);
    }
}

// ---------------- GEMMs: W staged in LDS, dis-scaled bf16 outputs ----------------

// hb'[row] = bf16( dis[row] * (x @ W1)[row] )  (32 rows/block, thread = 4r x 4c)
__global__ __launch_bounds__(256) void k_gemm1(const float* __restrict__ x,
                                               const float* __restrict__ W1,
                                               const float* __restrict__ dis,
                                               ushort* __restrict__ hb) {
    __shared__ float wsh[128 * 128];   // 64 KB
    __shared__ float xs[32 * 128];     // 16 KB
    const int t = threadIdx.x;
    {
        const float4* Wv = (const float4*)W1;
        float4* Sv = (float4*)wsh;
#pragma unroll
        for (int i = 0; i < 16; ++i) Sv[i * 256 + t] = Wv[i * 256 + t];
    }
    const int row0 = blockIdx.x * 32;
    {
        const float4* Xv = (const float4*)(x + (size_t)row0 * 128);
        float4* Sv = (float4*)xs;
#pragma unroll
        for (int i = 0; i < 4; ++i) Sv[i * 256 + t] = Xv[i * 256 + t];
    }
    __syncthreads();
    const int c4 = (t & 31) * 4;
    const int r0 = (t >> 5) * 4;
    float4 a0{0,0,0,0}, a1{0,0,0,0}, a2{0,0,0,0}, a3{0,0,0,0};
#pragma unroll 4
    for (int k = 0; k < 128; ++k) {
        float4 w = *(const float4*)&wsh[k * 128 + c4];
        float x0 = xs[(r0 + 0) * 128 + k];
        float x1 = xs[(r0 + 1) * 128 + k];
        float x2 = xs[(r0 + 2) * 128 + k];
        float x3 = xs[(r0 + 3) * 128 + k];
        a0.x = fmaf(x0, w.x, a0.x); a0.y = fmaf(x0, w.y, a0.y);
        a0.z = fmaf(x0, w.z, a0.z); a0.w = fmaf(x0, w.w, a0.w);
        a1.x = fmaf(x1, w.x, a1.x); a1.y = fmaf(x1, w.y, a1.y);
        a1.z = fmaf(x1, w.z, a1.z); a1.w = fmaf(x1, w.w, a1.w);
        a2.x = fmaf(x2, w.x, a2.x); a2.y = fmaf(x2, w.y, a2.y);
        a2.z = fmaf(x2, w.z, a2.z); a2.w = fmaf(x2, w.w, a2.w);
        a3.x = fmaf(x3, w.x, a3.x); a3.y = fmaf(x3, w.y, a3.y);
        a3.z = fmaf(x3, w.z, a3.z); a3.w = fmaf(x3, w.w, a3.w);
    }
    const float d0 = dis[row0 + r0], d1 = dis[row0 + r0 + 1];
    const float d2 = dis[row0 + r0 + 2], d3 = dis[row0 + r0 + 3];
    size_t base = (size_t)(row0 + r0) * 128 + c4;
    ushort4 u;
    u.x = f2bf(a0.x * d0); u.y = f2bf(a0.y * d0); u.z = f2bf(a0.z * d0); u.w = f2bf(a0.w * d0);
    *(ushort4*)&hb[base] = u;
    u.x = f2bf(a1.x * d1); u.y = f2bf(a1.y * d1); u.z = f2bf(a1.z * d1); u.w = f2bf(a1.w * d1);
    *(ushort4*)&hb[base + 128] = u;
    u.x = f2bf(a2.x * d2); u.y = f2bf(a2.y * d2); u.z = f2bf(a2.z * d2); u.w = f2bf(a2.w * d2);
    *(ushort4*)&hb[base + 256] = u;
    u.x = f2bf(a3.x * d3); u.y = f2bf(a3.y * d3); u.z = f2bf(a3.z * d3); u.w = f2bf(a3.w * d3);
    *(ushort4*)&hb[base + 384] = u;
}

// gb'[row] = bf16( dis[row] * (ab @ W2)[row] ) ; ab = relu'd bf16 (32 rows/block)
__global__ __launch_bounds__(256) void k_gemm2(const uint* __restrict__ ab,
                                               const float* __restrict__ W2,
                                               const float* __restrict__ dis,
                                               ushort* __restrict__ gb) {
    __shared__ float wsh[128 * 64];    // 32 KB
    __shared__ float xs[32 * 132];     // padded stride 132
    const int t = threadIdx.x;
    {
        const float4* Wv = (const float4*)W2;
        float4* Sv = (float4*)wsh;
#pragma unroll
        for (int i = 0; i < 8; ++i) Sv[i * 256 + t] = Wv[i * 256 + t];
    }
    const int row0 = blockIdx.x * 32;
    {
        const uint4* Xv = (const uint4*)(ab + (size_t)row0 * 64);  // 8 bf16 per uint4
#pragma unroll
        for (int i = 0; i < 2; ++i) {
            int f = i * 256 + t;               // uint4 index; flat elem = f*8
            uint4 vv = Xv[f];
            int row = f >> 4, col = (f & 15) * 8;
            float* d = &xs[row * 132 + col];
            d[0] = bf2f(vv.x & 0xffffu); d[1] = bf2f(vv.x >> 16);
            d[2] = bf2f(vv.y & 0xffffu); d[3] = bf2f(vv.y >> 16);
            d[4] = bf2f(vv.z & 0xffffu); d[5] = bf2f(vv.z >> 16);
            d[6] = bf2f(vv.w & 0xffffu); d[7] = bf2f(vv.w >> 16);
        }
    }
    __syncthreads();
    const int c4 = (t & 15) * 4;
    const int r0 = (t >> 4) * 2;
    float4 a0{0,0,0,0}, a1{0,0,0,0};
#pragma unroll 4
    for (int k = 0; k < 128; ++k) {
        float4 w = *(const float4*)&wsh[k * 64 + c4];
        float x0 = xs[(r0 + 0) * 132 + k];
        float x1 = xs[(r0 + 1) * 132 + k];
        a0.x = fmaf(x0, w.x, a0.x); a0.y = fmaf(x0, w.y, a0.y);
        a0.z = fmaf(x0, w.z, a0.z); a0.w = fmaf(x0, w.w, a0.w);
        a1.x = fmaf(x1, w.x, a1.x); a1.y = fmaf(x1, w.y, a1.y);
        a1.z = fmaf(x1, w.z, a1.z); a1.w = fmaf(x1, w.w, a1.w);
    }
    const float d0 = dis[row0 + r0], d1 = dis[row0 + r0 + 1];
    size_t base = (size_t)(row0 + r0) * 64 + c4;
    ushort4 u;
    u.x = f2bf(a0.x * d0); u.y = f2bf(a0.y * d0); u.z = f2bf(a0.z * d0); u.w = f2bf(a0.w * d0);
    *(ushort4*)&gb[base] = u;
    u.x = f2bf(a1.x * d1); u.y = f2bf(a1.y * d1); u.z = f2bf(a1.z * d1); u.w = f2bf(a1.w * d1);
    *(ushort4*)&gb[base + 64] = u;
}

// ---- CSR aggregation: 2 nodes/wave (one per 32-lane half), 4-edge unroll ----

// ab[v] = relu( b1 + dis[v] * ( hb'[v] + sum_{s in N(v)} hb'[s] ) )  as bf16
// lane: half = lane>>5 selects node, q = lane&31 covers dims 4q..4q+3 (uint2)
__global__ void k_agg1(const int* __restrict__ rowptr, const int* __restrict__ ssrc,
                       const float* __restrict__ dis, const uint2* __restrict__ hb2,
                       const float* __restrict__ b1, uint2* __restrict__ ab2) {
    const int t = threadIdx.x;
    const int lane = t & 63;
    const int q = lane & 31;
    const int v = blockIdx.x * 8 + ((t >> 6) << 1) + (lane >> 5);
    float4 accA, accB = {0.f, 0.f, 0.f, 0.f};
    {
        uint2 pv = hb2[(size_t)v * 32 + q];
        accA.x = bf2f(pv.x & 0xffffu); accA.y = bf2f(pv.x >> 16);
        accA.z = bf2f(pv.y & 0xffffu); accA.w = bf2f(pv.y >> 16);
    }
    int e = rowptr[v];
    const int end = rowptr[v + 1];
    while (e < end) {
        int m = end - e; if (m > 32) m = 32;
        int s = (q < m) ? ssrc[e + q] : 0;
        int i = 0;
        for (; i + 4 <= m; i += 4) {
            int s0 = __shfl(s, i + 0, 32);
            int s1 = __shfl(s, i + 1, 32);
            int s2 = __shfl(s, i + 2, 32);
            int s3 = __shfl(s, i + 3, 32);
            uint2 p0 = hb2[(size_t)s0 * 32 + q];
            uint2 p1 = hb2[(size_t)s1 * 32 + q];
            uint2 p2 = hb2[(size_t)s2 * 32 + q];
            uint2 p3 = hb2[(size_t)s3 * 32 + q];
            accA.x += bf2f(p0.x & 0xffffu); accA.y += bf2f(p0.x >> 16);
            accA.z += bf2f(p0.y & 0xffffu); accA.w += bf2f(p0.y >> 16);
            accB.x += bf2f(p1.x & 0xffffu); accB.y += bf2f(p1.x >> 16);
            accB.z += bf2f(p1.y & 0xffffu); accB.w += bf2f(p1.y >> 16);
            accA.x += bf2f(p2.x & 0xffffu); accA.y += bf2f(p2.x >> 16);
            accA.z += bf2f(p2.y & 0xffffu); accA.w += bf2f(p2.y >> 16);
            accB.x += bf2f(p3.x & 0xffffu); accB.y += bf2f(p3.x >> 16);
            accB.z += bf2f(p3.y & 0xffffu); accB.w += bf2f(p3.y >> 16);
        }
        for (; i < m; ++i) {
            int s0 = __shfl(s, i, 32);
            uint2 p0 = hb2[(size_t)s0 * 32 + q];
            accA.x += bf2f(p0.x & 0xffffu); accA.y += bf2f(p0.x >> 16);
            accA.z += bf2f(p0.y & 0xffffu); accA.w += bf2f(p0.y >> 16);
        }
        e += m;
    }
    const float dv = dis[v];
    const float4 bb = ((const float4*)b1)[q];
    float ox = fmaxf(fmaf(dv, accA.x + accB.x, bb.x), 0.f);
    float oy = fmaxf(fmaf(dv, accA.y + accB.y, bb.y), 0.f);
    float oz = fmaxf(fmaf(dv, accA.z + accB.z, bb.z), 0.f);
    float ow = fmaxf(fmaf(dv, accA.w + accB.w, bb.w), 0.f);
    uint2 o;
    o.x = ((uint)f2bf(oy) << 16) | (uint)f2bf(ox);
    o.y = ((uint)f2bf(ow) << 16) | (uint)f2bf(oz);
    ab2[(size_t)v * 32 + q] = o;
}

// out[v] = b2 + dis[v] * ( gb'[v] + sum gb'[s] ) ; lane q covers dims 2q,2q+1 (uint)
__global__ void k_agg2(const int* __restrict__ rowptr, const int* __restrict__ ssrc,
                       const float* __restrict__ dis, const uint* __restrict__ gbu,
                       const float* __restrict__ b2, float* __restrict__ out) {
    const int t = threadIdx.x;
    const int lane = t & 63;
    const int q = lane & 31;
    const int v = blockIdx.x * 8 + ((t >> 6) << 1) + (lane >> 5);
    float2 accA, accB = {0.f, 0.f};
    {
        uint pv = gbu[(size_t)v * 32 + q];
        accA.x = bf2f(pv & 0xffffu); accA.y = bf2f(pv >> 16);
    }
    int e = rowptr[v];
    const int end = rowptr[v + 1];
    while (e < end) {
        int m = end - e; if (m > 32) m = 32;
        int s = (q < m) ? ssrc[e + q] : 0;
        int i = 0;
        for (; i + 4 <= m; i += 4) {
            int s0 = __shfl(s, i + 0, 32);
            int s1 = __shfl(s, i + 1, 32);
            int s2 = __shfl(s, i + 2, 32);
            int s3 = __shfl(s, i + 3, 32);
            uint p0 = gbu[(size_t)s0 * 32 + q];
            uint p1 = gbu[(size_t)s1 * 32 + q];
            uint p2 = gbu[(size_t)s2 * 32 + q];
            uint p3 = gbu[(size_t)s3 * 32 + q];
            accA.x += bf2f(p0 & 0xffffu); accA.y += bf2f(p0 >> 16);
            accB.x += bf2f(p1 & 0xffffu); accB.y += bf2f(p1 >> 16);
            accA.x += bf2f(p2 & 0xffffu); accA.y += bf2f(p2 >> 16);
            accB.x += bf2f(p3 & 0xffffu); accB.y += bf2f(p3 >> 16);
        }
        for (; i < m; ++i) {
            int s0 = __shfl(s, i, 32);
            uint p0 = gbu[(size_t)s0 * 32 + q];
            accA.x += bf2f(p0 & 0xffffu); accA.y += bf2f(p0 >> 16);
        }
        e += m;
    }
    const float dv = dis[v];
    const float2 bb = ((const float2*)b2)[q];
    float2 o;
    o.x = fmaf(dv, accA.x + accB.x, bb.x);
    o.y = fmaf(dv, accA.y + accB.y, bb.y);
    ((float2*)out)[(size_t)v * 32 + q] = o;
}

// ---------------- launch ----------------

extern "C" void kernel_launch(void* const* d_in, const int* in_sizes, int n_in,
                              void* d_out, int out_size, void* d_ws, size_t ws_size,
                              hipStream_t stream) {
    const float* x  = (const float*)d_in[0];
    const float* W1 = (const float*)d_in[1];
    const float* b1 = (const float*)d_in[2];
    const float* W2 = (const float*)d_in[3];
    const float* b2 = (const float*)d_in[4];
    const int*   ei = (const int*)d_in[5];
    const int* src = ei;
    const int* dst = ei + EDGES;
    float* out = (float*)d_out;

    char* w = (char*)d_ws;
    int*    hist   = (int*)w;    w += (size_t)NCH * NBUCK * 4 + 256;  // pad
    int*    bstart = (int*)w;    w += 256 * 4;
    int*    rowptr = (int*)w;    w += 100004 * 4;
    float*  dis    = (float*)w;  w += 100000 * 4 + 16;
    uint*   binned = (uint*)w;   w += (size_t)EDGES * 4;
    int*    ssrc   = (int*)w;    w += (size_t)EDGES * 4;
    ushort* hb     = (ushort*)w; w += (size_t)NODES * 128 * 2;
    uint*   ab     = (uint*)w;   w += (size_t)NODES * 64 * 4;
    ushort* gb     = (ushort*)w; w += (size_t)NODES * 64 * 2;

    k_hist   <<<NCH, 256, 0, stream>>>(dst, hist);
    k_offsets<<<1, 256, 0, stream>>>(hist, bstart, rowptr);
    k_bin    <<<NCH, 256, 0, stream>>>(src, dst, hist, binned);
    k_build  <<<NBUCK, 256, 0, stream>>>(binned, bstart, rowptr, dis, ssrc);

    k_gemm1  <<<NODES / 32, 256, 0, stream>>>(x, W1, dis, hb);
    k_agg1   <<<NODES / 8, 256, 0, stream>>>(rowptr, ssrc, dis, (const uint2*)hb, b1, (uint2*)ab);
    k_gemm2  <<<NODES / 32, 256, 0, stream>>>(ab, W2, dis, gb);
    k_agg2   <<<NODES / 8, 256, 0, stream>>>(rowptr, ssrc, dis, (const uint*)gb, b2, out);
}